// Round 15
// baseline (245.822 us; speedup 1.0000x reference)
//
#include <hip/hip_runtime.h>
#include <hip/hip_bf16.h>

// x: [2, 2048, 1024] f32; mask: [2, 2048, 2048] f32; W_qkv: [1024, 3072] f32
// W_out: [1024, 1024] f32; b_out: [1024] f32; out: [2, 2048, 1024] f32
#define BATCH 2
#define SEQ   2048
#define DIM   1024
#define HEADS 16
#define DH    64
#define N_QKV 3072
#define M_TOT 4096
#define SCALE 0.125f
#define EPS   1e-10f
#define LOG2E 1.442695041f

typedef __attribute__((ext_vector_type(8))) _Float16 half8;
typedef __attribute__((ext_vector_type(4))) float f32x4;

static __device__ __forceinline__ unsigned short f2h(float f) {
    _Float16 h = (_Float16)f;
    return __builtin_bit_cast(unsigned short, h);
}
static __device__ __forceinline__ unsigned int pkrtz(float a, float b) {
#if defined(__has_builtin) && __has_builtin(__builtin_amdgcn_cvt_pkrtz)
    return __builtin_bit_cast(unsigned int, __builtin_amdgcn_cvt_pkrtz(a, b));
#else
    return (unsigned int)f2h(a) | ((unsigned int)f2h(b) << 16);
#endif
}
static __device__ __forceinline__ void glds16(const void* g, void* l) {
    __builtin_amdgcn_global_load_lds((const __attribute__((address_space(1))) void*)g,
                                     (__attribute__((address_space(3))) void*)l,
                                     16, 0, 0);
}

// ---------------------------------------------------------------------------
// Merged pre-pass: one launch, 4 independent jobs selected by block range.
//   [0,4096)      convert x fp32 -> fp16
//   [4096,7168)   transpose W_qkv -> WqT fp16 [n][k]
//   [7168,8192)   transpose W_out -> WoT fp16 [n][k]
//   [8192,8448)   pack mask bits (S^T layout, r11-verified)
// ---------------------------------------------------------------------------
__global__ __launch_bounds__(256) void prepass(const float* __restrict__ x,
                                               unsigned short* __restrict__ xh,
                                               const float* __restrict__ Wq,
                                               unsigned short* __restrict__ WqT,
                                               const float* __restrict__ Wo,
                                               unsigned short* __restrict__ WoT,
                                               const float* __restrict__ mask,
                                               unsigned short* __restrict__ mbits) {
    const int bid = blockIdx.x;
    const int t   = threadIdx.x;
    __shared__ float tile[32][33];
    __shared__ unsigned char flags[16][256];

    if (bid < 4096) {
        // ---- convert x -> fp16 ----
        const int i = bid * 256 + t;
        float4 v = reinterpret_cast<const float4*>(x)[i];
        uint2 o;
        o.x = pkrtz(v.x, v.y);
        o.y = pkrtz(v.z, v.w);
        reinterpret_cast<uint2*>(xh)[i] = o;
    } else if (bid < 8192) {
        // ---- transpose W (fp32 [k][n] -> fp16 [n][k]) ----
        const float* src; unsigned short* th; int rows, cols, bx;
        if (bid < 7168) { src = Wq; th = WqT; rows = 1024; cols = 3072; bx = bid - 4096;
        } else          { src = Wo; th = WoT; rows = 1024; cols = 1024; bx = bid - 7168; }
        const int nbx = cols / 32;
        const int c0 = (bx % nbx) * 32, r0 = (bx / nbx) * 32;
        const int tx = t & 31, ty = t >> 5;
        #pragma unroll
        for (int i = ty; i < 32; i += 8)
            tile[i][tx] = src[(long)(r0 + i) * cols + c0 + tx];
        __syncthreads();
        #pragma unroll
        for (int i = ty; i < 32; i += 8)
            th[(long)(c0 + i) * rows + r0 + tx] = f2h(tile[tx][i]);
    } else {
        // ---- pack mask bits ----
        const int bx = bid - 8192;
        const int it = bx & 127;
        const int bb = bx >> 7;
        const int R0 = it * 16;
        const int tl = t >> 6, ln = t & 63;
        for (int c0 = 0; c0 < SEQ; c0 += 256) {
            #pragma unroll
            for (int rr = 0; rr < 16; ++rr)
                flags[rr][t] = mask[((long)bb * SEQ + R0 + rr) * SEQ + c0 + t] != 0.f;
            __syncthreads();
            unsigned int bits = 0;
            #pragma unroll
            for (int nt = 0; nt < 4; ++nt)
                #pragma unroll
                for (int r = 0; r < 4; ++r)
                    bits |= (unsigned int)flags[ln & 15][tl * 64 + nt * 16 + ((ln >> 4) << 2) + r]
                            << (nt * 4 + r);
            mbits[(((long)bb * 128 + it) * 32 + (c0 >> 6) + tl) * 64 + ln] = (unsigned short)bits;
            __syncthreads();
        }
    }
}

// ---------------------------------------------------------------------------
// GEMM 1: plain fp16 MFMA, 64x128 tiles, BK=64, XOR-swizzled LDS (r14
// verified). NOTE: q is written pre-scaled by SCALE*LOG2E so the attention
// QK^T MFMA emits s*log2e directly (bare v_exp_f32, no fmaf, no shift).
// ---------------------------------------------------------------------------
__global__ __launch_bounds__(256, 4) void gemm_qkv_f16(
    const unsigned short* __restrict__ Ahg, const unsigned short* __restrict__ Bhg,
    unsigned short* __restrict__ qb, unsigned short* __restrict__ kb,
    unsigned short* __restrict__ vtb) {
    __shared__ __align__(16) unsigned short As[64 * 64];    // 8 KB
    __shared__ __align__(16) unsigned short Bs[128 * 64];   // 16 KB

    const int n0   = blockIdx.x * 128;
    const int m0   = blockIdx.y * 64;
    const int wave = threadIdx.x >> 6;      // n-quarter
    const int lane = threadIdx.x & 63;
    const int l16  = lane & 15;
    const int g    = lane >> 4;
    const int sw   = l16 & 7;

    const int sr8 = lane >> 3;
    const int scg = (lane & 7) ^ sr8;

    f32x4 acc[4][2] = {};                   // [mt][nt]

    for (int k0 = 0; k0 < DIM; k0 += 64) {
        #pragma unroll
        for (int i = 0; i < 2; ++i) {
            const int row = wave * 16 + i * 8;
            glds16(Ahg + (long)(m0 + row + sr8) * DIM + k0 + scg * 8, &As[row * 64]);
        }
        #pragma unroll
        for (int i = 0; i < 4; ++i) {
            const int row = wave * 32 + i * 8;
            glds16(Bhg + (long)(n0 + row + sr8) * DIM + k0 + scg * 8, &Bs[row * 64]);
        }
        __syncthreads();

        half8 a[4][2];
        #pragma unroll
        for (int mt = 0; mt < 4; ++mt) {
            const int rbase = (mt * 16 + l16) * 64;
            #pragma unroll
            for (int kc = 0; kc < 2; ++kc)
                a[mt][kc] = *reinterpret_cast<const half8*>(
                    &As[rbase + (((kc * 4 + g) ^ sw) * 8)]);
        }
        #pragma unroll
        for (int nt = 0; nt < 2; ++nt) {
            const int rbase = (wave * 32 + nt * 16 + l16) * 64;
            const half8 b0 = *reinterpret_cast<const half8*>(&Bs[rbase + (((0 + g) ^ sw) * 8)]);
            const half8 b1 = *reinterpret_cast<const half8*>(&Bs[rbase + (((4 + g) ^ sw) * 8)]);
            #pragma unroll
            for (int mt = 0; mt < 4; ++mt) {
                acc[mt][nt] = __builtin_amdgcn_mfma_f32_16x16x32_f16(a[mt][0], b0, acc[mt][nt], 0, 0, 0);
                acc[mt][nt] = __builtin_amdgcn_mfma_f32_16x16x32_f16(a[mt][1], b1, acc[mt][nt], 0, 0, 0);
            }
        }
        __syncthreads();
    }

    #pragma unroll
    for (int nt = 0; nt < 2; ++nt) {
        const int n     = n0 + wave * 32 + nt * 16 + l16;
        const int which = n >> 10;
        const int rem   = n & 1023;
        const int head  = rem >> 6;
        const int d     = rem & 63;
        #pragma unroll
        for (int mt = 0; mt < 4; ++mt) {
            #pragma unroll
            for (int r = 0; r < 4; ++r) {
                const int m  = m0 + mt * 16 + g * 4 + r;
                const int bb = m >> 11;
                const int li = m & 2047;
                const int bh_i = bb * HEADS + head;
                const float val = acc[mt][nt][r];
                if (which == 0)
                    qb[((long)bh_i * SEQ + li) * DH + d] = f2h(val * (SCALE * LOG2E));
                else if (which == 1)
                    kb[((long)bh_i * SEQ + li) * DH + d] = f2h(val);
                else
                    vtb[((long)bh_i * DH + d) * SEQ + li] = f2h(val);
            }
        }
    }
}

// ---------------------------------------------------------------------------
// GEMM 2: plain fp16 MFMA, 64x64 tiles, BK=64, XOR-swizzled (r14 verified).
// ---------------------------------------------------------------------------
__global__ __launch_bounds__(256, 4) void gemm_out_f16(
    const unsigned short* __restrict__ Ahg, const unsigned short* __restrict__ Bhg,
    const float* __restrict__ bias, float* __restrict__ out) {
    __shared__ __align__(16) unsigned short As[64 * 64];
    __shared__ __align__(16) unsigned short Bs[64 * 64];

    const int n0   = blockIdx.x * 64;
    const int m0   = blockIdx.y * 64;
    const int wave = threadIdx.x >> 6;
    const int lane = threadIdx.x & 63;
    const int l16  = lane & 15;
    const int g    = lane >> 4;
    const int wm   = wave & 1;
    const int wn   = wave >> 1;
    const int sw   = l16 & 7;

    const int sr8 = lane >> 3;
    const int scg = (lane & 7) ^ sr8;

    f32x4 acc[2][2] = {};

    for (int k0 = 0; k0 < DIM; k0 += 64) {
        #pragma unroll
        for (int i = 0; i < 2; ++i) {
            const int row = wave * 16 + i * 8;
            glds16(Ahg + (long)(m0 + row + sr8) * DIM + k0 + scg * 8, &As[row * 64]);
            glds16(Bhg + (long)(n0 + row + sr8) * DIM + k0 + scg * 8, &Bs[row * 64]);
        }
        __syncthreads();

        half8 a[2][2];
        #pragma unroll
        for (int mt = 0; mt < 2; ++mt) {
            const int rbase = (wm * 32 + mt * 16 + l16) * 64;
            #pragma unroll
            for (int kc = 0; kc < 2; ++kc)
                a[mt][kc] = *reinterpret_cast<const half8*>(
                    &As[rbase + (((kc * 4 + g) ^ sw) * 8)]);
        }
        #pragma unroll
        for (int nt = 0; nt < 2; ++nt) {
            const int rbase = (wn * 32 + nt * 16 + l16) * 64;
            const half8 b0 = *reinterpret_cast<const half8*>(&Bs[rbase + (((0 + g) ^ sw) * 8)]);
            const half8 b1 = *reinterpret_cast<const half8*>(&Bs[rbase + (((4 + g) ^ sw) * 8)]);
            #pragma unroll
            for (int mt = 0; mt < 2; ++mt) {
                acc[mt][nt] = __builtin_amdgcn_mfma_f32_16x16x32_f16(a[mt][0], b0, acc[mt][nt], 0, 0, 0);
                acc[mt][nt] = __builtin_amdgcn_mfma_f32_16x16x32_f16(a[mt][1], b1, acc[mt][nt], 0, 0, 0);
            }
        }
        __syncthreads();
    }

    #pragma unroll
    for (int nt = 0; nt < 2; ++nt) {
        const int n  = n0 + wn * 32 + nt * 16 + l16;
        const float bv = bias[n];
        #pragma unroll
        for (int mt = 0; mt < 2; ++mt) {
            #pragma unroll
            for (int r = 0; r < 4; ++r) {
                const int m = m0 + wm * 32 + mt * 16 + g * 4 + r;
                out[(long)m * DIM + n] = acc[mt][nt][r] + bv;
            }
        }
    }
}

// ---------------------------------------------------------------------------
// MFMA flash attention v7.1: r11-verified v7 structure; q pre-scaled by
// log2e so p = exp2(s') directly (no fmaf, no shift -- p = e^s is in
// [e^-7, e^7], fp16-safe; row-constant factors cancel in O/Z).
// ---------------------------------------------------------------------------
__global__ __launch_bounds__(512, 6) void attn_mfma(const unsigned short* __restrict__ qb,
                                                    const unsigned short* __restrict__ kb,
                                                    const unsigned short* __restrict__ vtb,
                                                    const unsigned short* __restrict__ mbits,
                                                    unsigned short* __restrict__ zh) {
    const int qt   = blockIdx.x;
    const int h    = blockIdx.y;
    const int bb   = blockIdx.z;
    const int bh   = bb * HEADS + h;
    const int wave = threadIdx.x >> 6;
    const int lane = threadIdx.x & 63;
    const int l16  = lane & 15;
    const int g    = lane >> 4;
    const int wm   = wave >> 1;             // row group 0..3
    const int wj   = wave & 1;              // j half

    const int myrow0 = qt * 64 + wm * 16;

    __shared__ __align__(16) unsigned short KV[2][2][64 * 64];  // [wj][K/V]
    __shared__ __align__(16) unsigned short Ps[8][16 * 64];

    const int sr8 = lane >> 3;
    const int scg = (lane & 7) ^ sr8;
    const int sw  = l16 & 7;

    const unsigned short* qptr = qb + ((long)bh * SEQ + myrow0 + l16) * DH + g * 8;
    const half8 q0 = *reinterpret_cast<const half8*>(qptr);
    const half8 q1 = *reinterpret_cast<const half8*>(qptr + 32);

    half8 ones;
    #pragma unroll
    for (int j = 0; j < 8; ++j) ones[j] = (_Float16)1.0f;

    f32x4 o[4] = {};
    f32x4 oz = {0.f, 0.f, 0.f, 0.f};         // Zpm via ones-row MFMA

    const unsigned short* mb =
        mbits + (((long)bb * 128 + qt * 4 + wm) * 32 + wj * 16) * 64 + lane;
    const long kbase = (long)bh * SEQ * DH;
    const long vbase = (long)bh * DH * SEQ;
    const int  jb    = wj * 1024;

    for (int it = 0; it < 16; ++it) {
        const int j0 = jb + it * 64;
        const unsigned int bits = mb[(long)it * 64];   // independent: issues early

        #pragma unroll
        for (int i = 0; i < 2; ++i) {
            const int row = wm * 16 + i * 8;           // wave-uniform
            glds16(kb  + kbase + (long)(j0 + row + sr8) * DH + scg * 8, &KV[wj][0][row * 64]);
            glds16(vtb + vbase + (long)(row + sr8) * SEQ + j0 + scg * 8, &KV[wj][1][row * 64]);
        }
        __syncthreads();

        // ---- S^T = K Q^T (already x log2e via q scale) ----
        f32x4 st[4];
        #pragma unroll
        for (int nt = 0; nt < 4; ++nt) {
            const int rbase = (nt * 16 + l16) * 64;
            const half8 k0 = *reinterpret_cast<const half8*>(&KV[wj][0][rbase + ((0 + g) ^ sw) * 8]);
            const half8 k1 = *reinterpret_cast<const half8*>(&KV[wj][0][rbase + (((4 + g) ^ sw) * 8)]);
            f32x4 acc = {0.f, 0.f, 0.f, 0.f};
            acc = __builtin_amdgcn_mfma_f32_16x16x32_f16(k0, q0, acc, 0, 0, 0);
            acc = __builtin_amdgcn_mfma_f32_16x16x32_f16(k1, q1, acc, 0, 0, 0);
            st[nt] = acc;
        }

        // ---- p = exp2(s'), bit-mask, pack 2xfp16 via cvt_pkrtz ----
        #pragma unroll
        for (int nt = 0; nt < 4; ++nt) {
            float pm[4];
            #pragma unroll
            for (int r = 0; r < 4; ++r) {
                const float p = __builtin_amdgcn_exp2f(st[nt][r]);
                pm[r] = ((bits >> (nt * 4 + r)) & 1u) ? p : 0.f;
            }
            uint2 pk;
            pk.x = pkrtz(pm[0], pm[1]);
            pk.y = pkrtz(pm[2], pm[3]);
            *reinterpret_cast<uint2*>(
                &Ps[wave][l16 * 64 + (((2 * nt + (g >> 1)) ^ sw) * 8) + (g & 1) * 4]) = pk;
        }

        // ---- O^T += V^T P^T ; Zpm row via ones-MFMA ----
        const half8 pb0 = *reinterpret_cast<const half8*>(&Ps[wave][l16 * 64 + ((0 + g) ^ sw) * 8]);
        const half8 pb1 = *reinterpret_cast<const half8*>(&Ps[wave][l16 * 64 + (((4 + g) ^ sw) * 8)]);
        #pragma unroll
        for (int dt = 0; dt < 4; ++dt) {
            const int vb = (dt * 16 + l16) * 64;
            const half8 v0 = *reinterpret_cast<const half8*>(&KV[wj][1][vb + ((0 + g) ^ sw) * 8]);
            const half8 v1 = *reinterpret_cast<const half8*>(&KV[wj][1][vb + (((4 + g) ^ sw) * 8)]);
            o[dt] = __builtin_amdgcn_mfma_f32_16x16x32_f16(v0, pb0, o[dt], 0, 0, 0);
            o[dt] = __builtin_amdgcn_mfma_f32_16x16x32_f16(v1, pb1, o[dt], 0, 0, 0);
        }
        oz = __builtin_amdgcn_mfma_f32_16x16x32_f16(ones, pb0, oz, 0, 0, 0);
        oz = __builtin_amdgcn_mfma_f32_16x16x32_f16(ones, pb1, oz, 0, 0, 0);
        __syncthreads();
    }

    // ---- combine the two j-halves (linear partials) ----
    float* cmb = (float*)&KV[0][0][0];      // 32 KB free after last barrier
    const int ci = wm * 16 + l16;
    if (wj == 1) {
        #pragma unroll
        for (int dt = 0; dt < 4; ++dt)
            *reinterpret_cast<f32x4*>(&cmb[ci * 68 + dt * 16 + g * 4]) = o[dt];
        if (g == 0) cmb[4352 + ci] = oz[0];
    }
    __syncthreads();
    if (wj == 0) {
        const float Z   = oz[0] + cmb[4352 + ci];
        const float inv = 1.f / (Z + 1e-30f);
        const long obase = ((long)bb * SEQ + myrow0 + l16) * DIM + h * DH;
        #pragma unroll
        for (int dt = 0; dt < 4; ++dt) {
            const f32x4 oc = *reinterpret_cast<const f32x4*>(&cmb[ci * 68 + dt * 16 + g * 4]);
            uint2 pk;
            pk.x = pkrtz((o[dt][0] + oc[0]) * inv, (o[dt][1] + oc[1]) * inv);
            pk.y = pkrtz((o[dt][2] + oc[2]) * inv, (o[dt][3] + oc[3]) * inv);
            *reinterpret_cast<uint2*>(zh + obase + dt * 16 + g * 4) = pk;
        }
    }
}

// ---------------------------------------------------------------------------
extern "C" void kernel_launch(void* const* d_in, const int* in_sizes, int n_in,
                              void* d_out, int out_size, void* d_ws, size_t ws_size,
                              hipStream_t stream) {
    const float* x     = (const float*)d_in[0];
    const float* mask  = (const float*)d_in[1];
    const float* W_qkv = (const float*)d_in[2];
    const float* W_out = (const float*)d_in[3];
    const float* b_out = (const float*)d_in[4];
    float* out = (float*)d_out;

    unsigned short* ws = (unsigned short*)d_ws;
    unsigned short* xh    = ws;                  // 4M fp16 (reused as z after gemm1)
    unsigned short* WqT   = xh    + 4194304;     // 3M fp16
    unsigned short* WoT   = WqT   + 3145728;     // 1M fp16
    unsigned short* qbu   = WoT   + 1048576;     // 4M fp16
    unsigned short* kbu   = qbu   + 4194304;     // 4M fp16
    unsigned short* vtb   = kbu   + 4194304;     // 4M fp16
    unsigned short* mbits = vtb   + 4194304;     // 0.5M -> 41 MB total
    unsigned short* zz    = xh;

    prepass<<<8448, 256, 0, stream>>>(x, xh, W_qkv, WqT, W_out, WoT, mask, mbits);

    gemm_qkv_f16<<<dim3(24, 64), 256, 0, stream>>>(xh, WqT, qbu, kbu, vtb);

    attn_mfma<<<dim3(SEQ / 64, HEADS, BATCH), 512, 0, stream>>>(qbu, kbu, vtb, mbits, zz);

    gemm_out_f16<<<dim3(16, 64), 256, 0, stream>>>(zz, WoT, b_out, out);
}

// Round 16
// 242.480 us; speedup vs baseline: 1.0138x; 1.0138x over previous
//
#include <hip/hip_runtime.h>
#include <hip/hip_bf16.h>

// x: [2, 2048, 1024] f32; mask: [2, 2048, 2048] f32; W_qkv: [1024, 3072] f32
// W_out: [1024, 1024] f32; b_out: [1024] f32; out: [2, 2048, 1024] f32
#define BATCH 2
#define SEQ   2048
#define DIM   1024
#define HEADS 16
#define DH    64
#define N_QKV 3072
#define M_TOT 4096
#define SCALE 0.125f
#define EPS   1e-10f
#define LOG2E 1.442695041f

typedef __attribute__((ext_vector_type(8))) _Float16 half8;
typedef __attribute__((ext_vector_type(4))) float f32x4;

static __device__ __forceinline__ unsigned short f2h(float f) {
    _Float16 h = (_Float16)f;
    return __builtin_bit_cast(unsigned short, h);
}
static __device__ __forceinline__ unsigned int pkrtz(float a, float b) {
#if defined(__has_builtin) && __has_builtin(__builtin_amdgcn_cvt_pkrtz)
    return __builtin_bit_cast(unsigned int, __builtin_amdgcn_cvt_pkrtz(a, b));
#else
    return (unsigned int)f2h(a) | ((unsigned int)f2h(b) << 16);
#endif
}
static __device__ __forceinline__ void glds16(const void* g, void* l) {
    __builtin_amdgcn_global_load_lds((const __attribute__((address_space(1))) void*)g,
                                     (__attribute__((address_space(3))) void*)l,
                                     16, 0, 0);
}

// ---------------------------------------------------------------------------
// Merged pre-pass (r15): one launch, 4 independent jobs by block range.
// ---------------------------------------------------------------------------
__global__ __launch_bounds__(256) void prepass(const float* __restrict__ x,
                                               unsigned short* __restrict__ xh,
                                               const float* __restrict__ Wq,
                                               unsigned short* __restrict__ WqT,
                                               const float* __restrict__ Wo,
                                               unsigned short* __restrict__ WoT,
                                               const float* __restrict__ mask,
                                               unsigned short* __restrict__ mbits) {
    const int bid = blockIdx.x;
    const int t   = threadIdx.x;
    __shared__ float tile[32][33];
    __shared__ unsigned char flags[16][256];

    if (bid < 4096) {
        const int i = bid * 256 + t;
        float4 v = reinterpret_cast<const float4*>(x)[i];
        uint2 o;
        o.x = pkrtz(v.x, v.y);
        o.y = pkrtz(v.z, v.w);
        reinterpret_cast<uint2*>(xh)[i] = o;
    } else if (bid < 8192) {
        const float* src; unsigned short* th; int rows, cols, bx;
        if (bid < 7168) { src = Wq; th = WqT; rows = 1024; cols = 3072; bx = bid - 4096;
        } else          { src = Wo; th = WoT; rows = 1024; cols = 1024; bx = bid - 7168; }
        const int nbx = cols / 32;
        const int c0 = (bx % nbx) * 32, r0 = (bx / nbx) * 32;
        const int tx = t & 31, ty = t >> 5;
        #pragma unroll
        for (int i = ty; i < 32; i += 8)
            tile[i][tx] = src[(long)(r0 + i) * cols + c0 + tx];
        __syncthreads();
        #pragma unroll
        for (int i = ty; i < 32; i += 8)
            th[(long)(c0 + i) * rows + r0 + tx] = f2h(tile[tx][i]);
    } else {
        const int bx = bid - 8192;
        const int it = bx & 127;
        const int bb = bx >> 7;
        const int R0 = it * 16;
        const int tl = t >> 6, ln = t & 63;
        for (int c0 = 0; c0 < SEQ; c0 += 256) {
            #pragma unroll
            for (int rr = 0; rr < 16; ++rr)
                flags[rr][t] = mask[((long)bb * SEQ + R0 + rr) * SEQ + c0 + t] != 0.f;
            __syncthreads();
            unsigned int bits = 0;
            #pragma unroll
            for (int nt = 0; nt < 4; ++nt)
                #pragma unroll
                for (int r = 0; r < 4; ++r)
                    bits |= (unsigned int)flags[ln & 15][tl * 64 + nt * 16 + ((ln >> 4) << 2) + r]
                            << (nt * 4 + r);
            mbits[(((long)bb * 128 + it) * 32 + (c0 >> 6) + tl) * 64 + ln] = (unsigned short)bits;
            __syncthreads();
        }
    }
}

// ---------------------------------------------------------------------------
// GEMM 1 v3: plain fp16 MFMA, 64x64 tiles, BK=64, XOR-swizzled LDS.
// Grid 48x64 = 3072 blocks (12/CU queued), __launch_bounds__(256,8) caps
// VGPR so 8 blocks/CU can be resident -- short-K (16 iters) makes these
// GEMMs barrier/latency-bound; co-resident blocks hide each other's drains
// (r13->r14 verified direction). Per wave-iter: 8 MFMA : 8 ds_read : 4 glds.
// q written pre-scaled by SCALE*LOG2E (attn uses bare exp2).
// ---------------------------------------------------------------------------
__global__ __launch_bounds__(256, 8) void gemm_qkv_f16(
    const unsigned short* __restrict__ Ahg, const unsigned short* __restrict__ Bhg,
    unsigned short* __restrict__ qb, unsigned short* __restrict__ kb,
    unsigned short* __restrict__ vtb) {
    __shared__ __align__(16) unsigned short As[64 * 64];    // 8 KB
    __shared__ __align__(16) unsigned short Bs[64 * 64];    // 8 KB

    const int n0   = blockIdx.x * 64;
    const int m0   = blockIdx.y * 64;
    const int wave = threadIdx.x >> 6;
    const int lane = threadIdx.x & 63;
    const int l16  = lane & 15;
    const int g    = lane >> 4;
    const int wm   = wave & 1;
    const int wn   = wave >> 1;
    const int sw   = l16 & 7;

    const int sr8 = lane >> 3;
    const int scg = (lane & 7) ^ sr8;

    f32x4 acc[2][2] = {};

    for (int k0 = 0; k0 < DIM; k0 += 64) {
        #pragma unroll
        for (int i = 0; i < 2; ++i) {
            const int row = wave * 16 + i * 8;
            glds16(Ahg + (long)(m0 + row + sr8) * DIM + k0 + scg * 8, &As[row * 64]);
            glds16(Bhg + (long)(n0 + row + sr8) * DIM + k0 + scg * 8, &Bs[row * 64]);
        }
        __syncthreads();

        half8 a[2][2];
        #pragma unroll
        for (int mt = 0; mt < 2; ++mt) {
            const int rbase = (wm * 32 + mt * 16 + l16) * 64;
            #pragma unroll
            for (int kc = 0; kc < 2; ++kc)
                a[mt][kc] = *reinterpret_cast<const half8*>(
                    &As[rbase + (((kc * 4 + g) ^ sw) * 8)]);
        }
        #pragma unroll
        for (int nt = 0; nt < 2; ++nt) {
            const int rbase = (wn * 32 + nt * 16 + l16) * 64;
            const half8 b0 = *reinterpret_cast<const half8*>(&Bs[rbase + (((0 + g) ^ sw) * 8)]);
            const half8 b1 = *reinterpret_cast<const half8*>(&Bs[rbase + (((4 + g) ^ sw) * 8)]);
            #pragma unroll
            for (int mt = 0; mt < 2; ++mt) {
                acc[mt][nt] = __builtin_amdgcn_mfma_f32_16x16x32_f16(a[mt][0], b0, acc[mt][nt], 0, 0, 0);
                acc[mt][nt] = __builtin_amdgcn_mfma_f32_16x16x32_f16(a[mt][1], b1, acc[mt][nt], 0, 0, 0);
            }
        }
        __syncthreads();
    }

    #pragma unroll
    for (int nt = 0; nt < 2; ++nt) {
        const int n     = n0 + wn * 32 + nt * 16 + l16;
        const int which = n >> 10;
        const int rem   = n & 1023;
        const int head  = rem >> 6;
        const int d     = rem & 63;
        #pragma unroll
        for (int mt = 0; mt < 2; ++mt) {
            #pragma unroll
            for (int r = 0; r < 4; ++r) {
                const int m  = m0 + wm * 32 + mt * 16 + g * 4 + r;
                const int bb = m >> 11;
                const int li = m & 2047;
                const int bh_i = bb * HEADS + head;
                const float val = acc[mt][nt][r];
                if (which == 0)
                    qb[((long)bh_i * SEQ + li) * DH + d] = f2h(val * (SCALE * LOG2E));
                else if (which == 1)
                    kb[((long)bh_i * SEQ + li) * DH + d] = f2h(val);
                else
                    vtb[((long)bh_i * DH + d) * SEQ + li] = f2h(val);
            }
        }
    }
}

// ---------------------------------------------------------------------------
// GEMM 2: plain fp16 MFMA, 64x64 tiles, BK=64, XOR-swizzled (r14 verified).
// ---------------------------------------------------------------------------
__global__ __launch_bounds__(256, 4) void gemm_out_f16(
    const unsigned short* __restrict__ Ahg, const unsigned short* __restrict__ Bhg,
    const float* __restrict__ bias, float* __restrict__ out) {
    __shared__ __align__(16) unsigned short As[64 * 64];
    __shared__ __align__(16) unsigned short Bs[64 * 64];

    const int n0   = blockIdx.x * 64;
    const int m0   = blockIdx.y * 64;
    const int wave = threadIdx.x >> 6;
    const int lane = threadIdx.x & 63;
    const int l16  = lane & 15;
    const int g    = lane >> 4;
    const int wm   = wave & 1;
    const int wn   = wave >> 1;
    const int sw   = l16 & 7;

    const int sr8 = lane >> 3;
    const int scg = (lane & 7) ^ sr8;

    f32x4 acc[2][2] = {};

    for (int k0 = 0; k0 < DIM; k0 += 64) {
        #pragma unroll
        for (int i = 0; i < 2; ++i) {
            const int row = wave * 16 + i * 8;
            glds16(Ahg + (long)(m0 + row + sr8) * DIM + k0 + scg * 8, &As[row * 64]);
            glds16(Bhg + (long)(n0 + row + sr8) * DIM + k0 + scg * 8, &Bs[row * 64]);
        }
        __syncthreads();

        half8 a[2][2];
        #pragma unroll
        for (int mt = 0; mt < 2; ++mt) {
            const int rbase = (wm * 32 + mt * 16 + l16) * 64;
            #pragma unroll
            for (int kc = 0; kc < 2; ++kc)
                a[mt][kc] = *reinterpret_cast<const half8*>(
                    &As[rbase + (((kc * 4 + g) ^ sw) * 8)]);
        }
        #pragma unroll
        for (int nt = 0; nt < 2; ++nt) {
            const int rbase = (wn * 32 + nt * 16 + l16) * 64;
            const half8 b0 = *reinterpret_cast<const half8*>(&Bs[rbase + (((0 + g) ^ sw) * 8)]);
            const half8 b1 = *reinterpret_cast<const half8*>(&Bs[rbase + (((4 + g) ^ sw) * 8)]);
            #pragma unroll
            for (int mt = 0; mt < 2; ++mt) {
                acc[mt][nt] = __builtin_amdgcn_mfma_f32_16x16x32_f16(a[mt][0], b0, acc[mt][nt], 0, 0, 0);
                acc[mt][nt] = __builtin_amdgcn_mfma_f32_16x16x32_f16(a[mt][1], b1, acc[mt][nt], 0, 0, 0);
            }
        }
        __syncthreads();
    }

    #pragma unroll
    for (int nt = 0; nt < 2; ++nt) {
        const int n  = n0 + wn * 32 + nt * 16 + l16;
        const float bv = bias[n];
        #pragma unroll
        for (int mt = 0; mt < 2; ++mt) {
            #pragma unroll
            for (int r = 0; r < 4; ++r) {
                const int m = m0 + wm * 32 + mt * 16 + g * 4 + r;
                out[(long)m * DIM + n] = acc[mt][nt][r] + bv;
            }
        }
    }
}

// ---------------------------------------------------------------------------
// MFMA flash attention v7.1 (r15 verified, 68 us): all-fp16 fragments, S^T
// orientation, q pre-scaled by log2e -> bare exp2; j-split x2 in-block
// (linear partials), P packed via cvt_pkrtz, Zpm via ones-row MFMA.
// ---------------------------------------------------------------------------
__global__ __launch_bounds__(512, 6) void attn_mfma(const unsigned short* __restrict__ qb,
                                                    const unsigned short* __restrict__ kb,
                                                    const unsigned short* __restrict__ vtb,
                                                    const unsigned short* __restrict__ mbits,
                                                    unsigned short* __restrict__ zh) {
    const int qt   = blockIdx.x;
    const int h    = blockIdx.y;
    const int bb   = blockIdx.z;
    const int bh   = bb * HEADS + h;
    const int wave = threadIdx.x >> 6;
    const int lane = threadIdx.x & 63;
    const int l16  = lane & 15;
    const int g    = lane >> 4;
    const int wm   = wave >> 1;             // row group 0..3
    const int wj   = wave & 1;              // j half

    const int myrow0 = qt * 64 + wm * 16;

    __shared__ __align__(16) unsigned short KV[2][2][64 * 64];  // [wj][K/V]
    __shared__ __align__(16) unsigned short Ps[8][16 * 64];

    const int sr8 = lane >> 3;
    const int scg = (lane & 7) ^ sr8;
    const int sw  = l16 & 7;

    const unsigned short* qptr = qb + ((long)bh * SEQ + myrow0 + l16) * DH + g * 8;
    const half8 q0 = *reinterpret_cast<const half8*>(qptr);
    const half8 q1 = *reinterpret_cast<const half8*>(qptr + 32);

    half8 ones;
    #pragma unroll
    for (int j = 0; j < 8; ++j) ones[j] = (_Float16)1.0f;

    f32x4 o[4] = {};
    f32x4 oz = {0.f, 0.f, 0.f, 0.f};         // Zpm via ones-row MFMA

    const unsigned short* mb =
        mbits + (((long)bb * 128 + qt * 4 + wm) * 32 + wj * 16) * 64 + lane;
    const long kbase = (long)bh * SEQ * DH;
    const long vbase = (long)bh * DH * SEQ;
    const int  jb    = wj * 1024;

    for (int it = 0; it < 16; ++it) {
        const int j0 = jb + it * 64;
        const unsigned int bits = mb[(long)it * 64];   // independent: issues early

        #pragma unroll
        for (int i = 0; i < 2; ++i) {
            const int row = wm * 16 + i * 8;           // wave-uniform
            glds16(kb  + kbase + (long)(j0 + row + sr8) * DH + scg * 8, &KV[wj][0][row * 64]);
            glds16(vtb + vbase + (long)(row + sr8) * SEQ + j0 + scg * 8, &KV[wj][1][row * 64]);
        }
        __syncthreads();

        // ---- S^T = K Q^T (already x log2e via q scale) ----
        f32x4 st[4];
        #pragma unroll
        for (int nt = 0; nt < 4; ++nt) {
            const int rbase = (nt * 16 + l16) * 64;
            const half8 k0 = *reinterpret_cast<const half8*>(&KV[wj][0][rbase + ((0 + g) ^ sw) * 8]);
            const half8 k1 = *reinterpret_cast<const half8*>(&KV[wj][0][rbase + (((4 + g) ^ sw) * 8)]);
            f32x4 acc = {0.f, 0.f, 0.f, 0.f};
            acc = __builtin_amdgcn_mfma_f32_16x16x32_f16(k0, q0, acc, 0, 0, 0);
            acc = __builtin_amdgcn_mfma_f32_16x16x32_f16(k1, q1, acc, 0, 0, 0);
            st[nt] = acc;
        }

        // ---- p = exp2(s'), bit-mask, pack 2xfp16 via cvt_pkrtz ----
        #pragma unroll
        for (int nt = 0; nt < 4; ++nt) {
            float pm[4];
            #pragma unroll
            for (int r = 0; r < 4; ++r) {
                const float p = __builtin_amdgcn_exp2f(st[nt][r]);
                pm[r] = ((bits >> (nt * 4 + r)) & 1u) ? p : 0.f;
            }
            uint2 pk;
            pk.x = pkrtz(pm[0], pm[1]);
            pk.y = pkrtz(pm[2], pm[3]);
            *reinterpret_cast<uint2*>(
                &Ps[wave][l16 * 64 + (((2 * nt + (g >> 1)) ^ sw) * 8) + (g & 1) * 4]) = pk;
        }

        // ---- O^T += V^T P^T ; Zpm row via ones-MFMA ----
        const half8 pb0 = *reinterpret_cast<const half8*>(&Ps[wave][l16 * 64 + ((0 + g) ^ sw) * 8]);
        const half8 pb1 = *reinterpret_cast<const half8*>(&Ps[wave][l16 * 64 + (((4 + g) ^ sw) * 8)]);
        #pragma unroll
        for (int dt = 0; dt < 4; ++dt) {
            const int vb = (dt * 16 + l16) * 64;
            const half8 v0 = *reinterpret_cast<const half8*>(&KV[wj][1][vb + ((0 + g) ^ sw) * 8]);
            const half8 v1 = *reinterpret_cast<const half8*>(&KV[wj][1][vb + (((4 + g) ^ sw) * 8)]);
            o[dt] = __builtin_amdgcn_mfma_f32_16x16x32_f16(v0, pb0, o[dt], 0, 0, 0);
            o[dt] = __builtin_amdgcn_mfma_f32_16x16x32_f16(v1, pb1, o[dt], 0, 0, 0);
        }
        oz = __builtin_amdgcn_mfma_f32_16x16x32_f16(ones, pb0, oz, 0, 0, 0);
        oz = __builtin_amdgcn_mfma_f32_16x16x32_f16(ones, pb1, oz, 0, 0, 0);
        __syncthreads();
    }

    // ---- combine the two j-halves (linear partials) ----
    float* cmb = (float*)&KV[0][0][0];      // 32 KB free after last barrier
    const int ci = wm * 16 + l16;
    if (wj == 1) {
        #pragma unroll
        for (int dt = 0; dt < 4; ++dt)
            *reinterpret_cast<f32x4*>(&cmb[ci * 68 + dt * 16 + g * 4]) = o[dt];
        if (g == 0) cmb[4352 + ci] = oz[0];
    }
    __syncthreads();
    if (wj == 0) {
        const float Z   = oz[0] + cmb[4352 + ci];
        const float inv = 1.f / (Z + 1e-30f);
        const long obase = ((long)bb * SEQ + myrow0 + l16) * DIM + h * DH;
        #pragma unroll
        for (int dt = 0; dt < 4; ++dt) {
            const f32x4 oc = *reinterpret_cast<const f32x4*>(&cmb[ci * 68 + dt * 16 + g * 4]);
            uint2 pk;
            pk.x = pkrtz((o[dt][0] + oc[0]) * inv, (o[dt][1] + oc[1]) * inv);
            pk.y = pkrtz((o[dt][2] + oc[2]) * inv, (o[dt][3] + oc[3]) * inv);
            *reinterpret_cast<uint2*>(zh + obase + dt * 16 + g * 4) = pk;
        }
    }
}

// ---------------------------------------------------------------------------
extern "C" void kernel_launch(void* const* d_in, const int* in_sizes, int n_in,
                              void* d_out, int out_size, void* d_ws, size_t ws_size,
                              hipStream_t stream) {
    const float* x     = (const float*)d_in[0];
    const float* mask  = (const float*)d_in[1];
    const float* W_qkv = (const float*)d_in[2];
    const float* W_out = (const float*)d_in[3];
    const float* b_out = (const float*)d_in[4];
    float* out = (float*)d_out;

    unsigned short* ws = (unsigned short*)d_ws;
    unsigned short* xh    = ws;                  // 4M fp16 (reused as z after gemm1)
    unsigned short* WqT   = xh    + 4194304;     // 3M fp16
    unsigned short* WoT   = WqT   + 3145728;     // 1M fp16
    unsigned short* qbu   = WoT   + 1048576;     // 4M fp16
    unsigned short* kbu   = qbu   + 4194304;     // 4M fp16
    unsigned short* vtb   = kbu   + 4194304;     // 4M fp16
    unsigned short* mbits = vtb   + 4194304;     // 0.5M -> 41 MB total
    unsigned short* zz    = xh;

    prepass<<<8448, 256, 0, stream>>>(x, xh, W_qkv, WqT, W_out, WoT, mask, mbits);

    gemm_qkv_f16<<<dim3(48, 64), 256, 0, stream>>>(xh, WqT, qbu, kbu, vtb);

    attn_mfma<<<dim3(SEQ / 64, HEADS, BATCH), 512, 0, stream>>>(qbu, kbu, vtb, mbits, zz);

    gemm_out_f16<<<dim3(16, 64), 256, 0, stream>>>(zz, WoT, b_out, out);
}